// Round 12
// baseline (158.927 us; speedup 1.0000x reference)
//
#include <hip/hip_runtime.h>
#include <string.h>

typedef _Float16 half2v __attribute__((ext_vector_type(2)));
typedef _Float16 half4  __attribute__((ext_vector_type(4)));
typedef _Float16 half8  __attribute__((ext_vector_type(8)));
typedef float    float4v __attribute__((ext_vector_type(4)));
typedef unsigned int uint4v __attribute__((ext_vector_type(4)));

#define HH 256
#define WW 256
#define HSTR 264   // R5-proven h_lds row stride (268 measured slower — R9)

static __device__ inline half2v pkrtz(float a, float b) {
    return __builtin_bit_cast(half2v, __builtin_amdgcn_cvt_pkrtz(a, b));
}

static __device__ inline half2v h2cast(unsigned u) {
    return __builtin_bit_cast(half2v, u);
}

static __device__ inline float fdot2f(half2v a, half2v b, float c) {
#if __has_builtin(__builtin_amdgcn_fdot2)
    return __builtin_amdgcn_fdot2(__builtin_bit_cast(__fp16 __attribute__((ext_vector_type(2))), a),
                                  __builtin_bit_cast(__fp16 __attribute__((ext_vector_type(2))), b),
                                  c, false);
#else
    return c + (float)a[0] * (float)b[0] + (float)a[1] * (float)b[1];
#endif
}

// ---------------- x (NCHW f32, 3ch) -> xh (NHWC f16, 16ch zero-padded) -----
__global__ __launch_bounds__(256) void xcvt(
    const float* __restrict__ x, _Float16* __restrict__ xh)
{
    int gid = blockIdx.x * 256 + threadIdx.x;      // n*65536 + y*256 + x
    int px = gid & 65535, n = gid >> 16;
    float r = x[n * 196608 + px];
    float g = x[n * 196608 + 65536 + px];
    float b = x[n * 196608 + 131072 + px];
    half2v p0 = pkrtz(r, g);
    half2v p1 = pkrtz(b, 0.f);
    unsigned u0, u1;
    memcpy(&u0, &p0, 4); memcpy(&u1, &p1, 4);
    uint4v v0 = {u0, u1, 0u, 0u};
    uint4v v1 = {0u, 0u, 0u, 0u};
    uint4v* dst = (uint4v*)&xh[(long)gid * 16];
    dst[0] = v0; dst[1] = v1;
}

// ---------------- fused weight packing (w2/b2 + conv layers) ---------------
__global__ __launch_bounds__(256) void pack_all(
    const float* __restrict__ w2, const float* __restrict__ b2,
    half8* __restrict__ w2p, float* __restrict__ b2p,
    const float* __restrict__ w0, const float* __restrict__ w1c,
    const float* __restrict__ w2c, const float* __restrict__ w3c,
    half8* __restrict__ wpk)
{
    int tid = blockIdx.x * 256 + threadIdx.x;
    if (tid < 13824) {
        int l  = tid & 63;
        int s  = (tid >> 6) & 7;
        int tt = tid >> 9;                           // tile 0..26
        int kk = tt / 3, c = tt % 3;
        int ci = l & 15;
        int col = (ci * 9 + kk) * 3 + c;
        int kbase = s * 32 + (l >> 4) * 8;
        half8 h;
#pragma unroll
        for (int j = 0; j < 8; ++j)
            h[j] = (_Float16)w2[(kbase + j) * 432 + col];
        w2p[tid] = h;

        if (tid < 432) {
            int tt2 = tid >> 4, ci2 = tid & 15;
            int kk2 = tt2 / 3, c2 = tt2 % 3;
            b2p[tid] = b2[(ci2 * 9 + kk2) * 3 + c2];
        }
    } else if (tid < 15104) {
        int t2 = tid - 13824;                        // < 1280
        int l = t2 & 63, s = (t2 >> 6) % 5, cv = t2 / 320;
        const float* w = (cv == 0) ? w0 : (cv == 1) ? w1c : (cv == 2) ? w2c : w3c;
        int CIN = (cv == 0) ? 3 : 16;
        int o = l & 15, hi = l >> 4;
        half8 h;
#pragma unroll
        for (int j = 0; j < 8; ++j) {
            int k = 32 * s + hi * 8 + j;
            int tap = k >> 4, ci = k & 15;
            float v = 0.f;
            if (tap < 9 && ci < CIN)
                v = w[((o * CIN + ci) * 3 + tap / 3) * 3 + tap % 3];
            h[j] = (_Float16)v;
        }
        wpk[t2] = h;
    }
}

// ---------------- conv 3x3 + ReLU via implicit-GEMM MFMA, NHWC f16 ---------
__global__ __launch_bounds__(256) void conv_mfma(
    const _Float16* __restrict__ in, const half8* __restrict__ wpk,
    const float* __restrict__ bias, _Float16* __restrict__ outp)
{
    __shared__ _Float16 tile[7][66][16];           // 14784 B

    const int t = threadIdx.x;
    const int bid = blockIdx.x;
    const int xt = bid & 3, yt = (bid >> 2) & 63, n = bid >> 8;
    const int x0 = xt * 64, y0 = yt * 4;

    for (int e = t; e < 462; e += 256) {           // 7 rows x 66 x, 32B chunks
        int xx = e % 66, row = e / 66;
        int gy = y0 + row - 1, gx = x0 + xx - 1;
        uint4v v0 = {0u,0u,0u,0u}, v1 = {0u,0u,0u,0u};
        if (gy >= 0 && gy < HH && gx >= 0 && gx < WW) {
            const uint4v* src = (const uint4v*)&in[(((long)(n*HH+gy))*WW + gx) * 16];
            v0 = src[0]; v1 = src[1];
        }
        uint4v* dst = (uint4v*)&tile[row][xx][0];
        dst[0] = v0; dst[1] = v1;
    }
    __syncthreads();

    const int wid = t >> 6, lane = t & 63;
    const int l15 = lane & 15, hi = lane >> 4;

    half8 af[5];
#pragma unroll
    for (int s = 0; s < 5; ++s) af[s] = wpk[s * 64 + lane];
    const float4v bini = *(const float4v*)&bias[hi * 4];

    const int ty = wid;
    const half8* bp = (const half8*)&tile[0][0][0];
#pragma unroll
    for (int tx = 0; tx < 4; ++tx) {
        float4v acc = bini;
#pragma unroll
        for (int s = 0; s < 5; ++s) {
            int tap = 2 * s + (hi >> 1);
            int dyq = (tap * 11) >> 5;             // tap / 3
            int dxr = tap - dyq * 3;
            int cell = (ty + dyq) * 66 + (tx * 16 + l15 + dxr);
            half8 bf = bp[cell * 2 + (hi & 1)];
            acc = __builtin_amdgcn_mfma_f32_16x16x32_f16(af[s], bf, acc, 0, 0, 0);
        }
        int gx = x0 + tx * 16 + l15, gy = y0 + ty;
        half2v p0 = pkrtz(fmaxf(acc[0], 0.f), fmaxf(acc[1], 0.f));
        half2v p1 = pkrtz(fmaxf(acc[2], 0.f), fmaxf(acc[3], 0.f));
        half4 ov = __builtin_shufflevector(p0, p1, 0, 1, 2, 3);
        *(half4*)&outp[(((long)(n*HH+gy))*WW + gx) * 16 + hi * 4] = ov;
    }
}

// ---- fused Pos2Weight MLP (MFMA) + locally-connected contraction ----------
// R11 base (mlp=142us; 64 arch + 64 acc VGPR = 2 blocks/CU) with ONE change:
// f_lds cell relayout. Each (dy,x) = 128B cell; u32 word (g*4+n)^((cell&7)<<2)
// holds ci-pair (2g,2g+1) of image n. Stage: 8 ds_write_b32/thread (2-way max
// bank aliasing = free). Epilogue: 2 ds_read_b128 per (tt,pg) whose u32 lanes
// ARE the per-n half2 operands (was 4 b64 + per-n addr math).
__global__ __launch_bounds__(512, 4) void mlp_lc_mfma(
    const float* __restrict__ pos, const float* __restrict__ w1,
    const float* __restrict__ b1,  const half8* __restrict__ w2p,
    const float* __restrict__ b2p, const _Float16* __restrict__ f,
    float* __restrict__ out)
{
    __shared__ __attribute__((aligned(16))) char smem[47872];
    _Float16* h_lds    = (_Float16*)smem;                  // [64][264] 33792 B
    unsigned* f_u32    = (unsigned*)(smem + 33792);        // 102 cells x 32 u32, 13056 B
    float*    pos_lds  = (float*)(smem + 33792 + 13056);   // [64][4] 1024 B
    float*    part_lds = (float*)smem;                     // [64][106] alias

    const int t = threadIdx.x;
    // XCD-chunked swizzle: each XCD owns a contiguous slab of logical work
    const int bid = blockIdx.x;
    const int lb  = (bid & 7) * 512 + (bid >> 3);
    const int p0  = lb * 64;
    const int t2  = p0 >> 9;                  // output row oy
    const int hh  = t2 >> 1;
    const int ww0 = (p0 >> 1) & (WW - 1);

    if (t < 192) pos_lds[(t / 3) * 4 + (t % 3)] = pos[p0 * 3 + t];

    // stage f: 408 threads = 102 (dy,x) cells x 4 n; 32B global chunk each,
    // scattered into the cell as 8 swizzled b32 words
    if (t < 408) {
        int n  = t & 3;
        int q  = t >> 2;                      // cell = dy*34 + x
        int x  = q % 34;
        int dy = q / 34;
        int gy = hh + dy - 1, gx = ww0 + x - 1;
        uint4v v0 = {0u,0u,0u,0u}, v1 = {0u,0u,0u,0u};
        if (gy >= 0 && gy < HH && gx >= 0 && gx < WW) {
            const uint4v* src = (const uint4v*)&f[(((long)(n*HH+gy))*WW + gx) * 16];
            v0 = src[0]; v1 = src[1];
        }
        const int base = q * 32;
        const int key  = (q & 7) << 2;
#pragma unroll
        for (int g = 0; g < 4; ++g)
            f_u32[base + ((g * 4 + n) ^ key)] = v0[g];
#pragma unroll
        for (int g = 4; g < 8; ++g)
            f_u32[base + ((g * 4 + n) ^ key)] = v1[g - 4];
    }
    __syncthreads();                          // pos + f ready

    // ---- h = relu(pos @ w1 + b1): 4 k x 8 pos per thread, b64 writes ----
    {
        const int k4 = (t & 63) * 4;          // lane-contiguous k block
        const int i0 = (t >> 6) * 8;          // 8 positions per thread
        const float4v w1r0 = *(const float4v*)&w1[k4];
        const float4v w1r1 = *(const float4v*)&w1[256 + k4];
        const float4v w1r2 = *(const float4v*)&w1[512 + k4];
        const float4v b1v  = *(const float4v*)&b1[k4];
#pragma unroll
        for (int i = i0; i < i0 + 8; ++i) {
            float4v pv = *(const float4v*)&pos_lds[i * 4];
            float a0 = fmaf(pv[0], w1r0[0], fmaf(pv[1], w1r1[0], fmaf(pv[2], w1r2[0], b1v[0])));
            float a1 = fmaf(pv[0], w1r0[1], fmaf(pv[1], w1r1[1], fmaf(pv[2], w1r2[1], b1v[1])));
            float a2 = fmaf(pv[0], w1r0[2], fmaf(pv[1], w1r1[2], fmaf(pv[2], w1r2[2], b1v[2])));
            float a3 = fmaf(pv[0], w1r0[3], fmaf(pv[1], w1r1[3], fmaf(pv[2], w1r2[3], b1v[3])));
            half2v q0 = pkrtz(fmaxf(a0, 0.f), fmaxf(a1, 0.f));
            half2v q1 = pkrtz(fmaxf(a2, 0.f), fmaxf(a3, 0.f));
            *(half4*)&h_lds[i * HSTR + k4] = __builtin_shufflevector(q0, q1, 0, 1, 2, 3);
        }
    }
    __syncthreads();                          // h ready

    // ---- GEMM: acc[tt][pg] = w2tile(tb+tt)^T @ h(pg) ----
    const int wid  = t >> 6;
    const int lane = t & 63;
    const int l15  = lane & 15, hi = lane >> 4;
    const int tb   = (wid <= 3) ? wid * 4 : 12 + (wid - 3) * 3;
    const int cnt  = (wid < 3) ? 4 : 3;

    float4v acc[4][4];
#pragma unroll
    for (int tt = 0; tt < 4; ++tt)
        if (tt < cnt) {
            float4v binit = *(const float4v*)&b2p[(tb + tt) * 16 + hi * 4];
#pragma unroll
            for (int pg = 0; pg < 4; ++pg) acc[tt][pg] = binit;
        }

    for (int ks = 0; ks < 8; ++ks) {
        half8 bfrag[4];
#pragma unroll
        for (int pg = 0; pg < 4; ++pg)
            bfrag[pg] = *(const half8*)&h_lds[(pg * 16 + l15) * HSTR + ks * 32 + hi * 8];
#pragma unroll
        for (int tt = 0; tt < 4; ++tt)
            if (tt < cnt) {
                half8 afrag = w2p[((tb + tt) * 8 + ks) * 64 + lane];
#pragma unroll
                for (int pg = 0; pg < 4; ++pg)
                    acc[tt][pg] = __builtin_amdgcn_mfma_f32_16x16x32_f16(
                        afrag, bfrag[pg], acc[tt][pg], 0, 0, 0);
            }
    }
    __syncthreads();   // all h reads done; part_lds (alias) may be written

    // ---- epilogue: b128 f reads, fdot2 contraction, reduce ------
    const int r3 = tb % 3;            // wave-uniform rgb rotation
    int dy_t[4], dx_t[4];
#pragma unroll
    for (int tt = 0; tt < 4; ++tt) {
        int kk = (tb + tt) / 3;
        dy_t[tt] = kk / 3;
        dx_t[tt] = kk % 3;
    }

#pragma unroll
    for (int pg = 0; pg < 4; ++pg) {
        const int posl = pg * 16 + l15;
        const int xloc = posl >> 1;

        float part[4][3];
#pragma unroll
        for (int n = 0; n < 4; ++n)
#pragma unroll
            for (int c = 0; c < 3; ++c) part[n][c] = 0.f;

#pragma unroll
        for (int tt = 0; tt < 4; ++tt)
            if (tt < cnt) {
                int x    = xloc + dx_t[tt];
                int cell = dy_t[tt] * 34 + x;
                int key  = cell & 7;
                const uint4v* fcell = (const uint4v*)(f_u32 + cell * 32);
                uint4v fv0 = fcell[(2 * hi) ^ key];       // ci 4hi,4hi+1, n=lane
                uint4v fv1 = fcell[(2 * hi + 1) ^ key];   // ci 4hi+2,4hi+3
                half2v ap = pkrtz(acc[tt][pg][0], acc[tt][pg][1]);
                half2v bq = pkrtz(acc[tt][pg][2], acc[tt][pg][3]);
                const int u = tt % 3;
#pragma unroll
                for (int n = 0; n < 4; ++n)
                    part[n][u] = fdot2f(h2cast(fv0[n]), ap,
                                 fdot2f(h2cast(fv1[n]), bq, part[n][u]));
            }

        float real[4][3];
        if (r3 == 0) {
#pragma unroll
            for (int n = 0; n < 4; ++n) {
                real[n][0] = part[n][0]; real[n][1] = part[n][1]; real[n][2] = part[n][2];
            }
        } else if (r3 == 1) {
#pragma unroll
            for (int n = 0; n < 4; ++n) {
                real[n][1] = part[n][0]; real[n][2] = part[n][1]; real[n][0] = part[n][2];
            }
        } else {
#pragma unroll
            for (int n = 0; n < 4; ++n) {
                real[n][2] = part[n][0]; real[n][0] = part[n][1]; real[n][1] = part[n][2];
            }
        }

#pragma unroll
        for (int n = 0; n < 4; ++n)
#pragma unroll
            for (int c = 0; c < 3; ++c) {
                float v = real[n][c];
                v += __shfl_xor(v, 16);
                v += __shfl_xor(v, 32);
                if (hi == 0)
                    part_lds[posl * 106 + (n * 3 + c) * 8 + wid] = v;
            }
    }
    __syncthreads();

    // ---- combine 8 waves' partials, add mean, store ----
    for (int e = t; e < 768; e += 512) {
        int posl = e & 63;
        int j = e >> 6;                       // n*3+c
        const float* pr = &part_lds[posl * 106 + j * 8];
        float4v v0 = *(const float4v*)pr;
        float4v v1 = *(const float4v*)(pr + 4);
        float v = v0[0] + v0[1] + v0[2] + v0[3] + v1[0] + v1[1] + v1[2] + v1[3];
        int n = j / 3, c = j - 3 * n;
        float mean = (c == 0) ? 114.4440f : (c == 1) ? 111.4605f : 103.0200f;
        out[((n * 3 + c) * 512 + t2) * 512 + (ww0 * 2 + posl)] = v + mean;
    }
}

extern "C" void kernel_launch(void* const* d_in, const int* in_sizes, int n_in,
                              void* d_out, int out_size, void* d_ws, size_t ws_size,
                              hipStream_t stream) {
    const float* x    = (const float*)d_in[0];
    const float* pos  = (const float*)d_in[1];
    const float* c0w  = (const float*)d_in[2];
    const float* c1w  = (const float*)d_in[4];
    const float* c2w  = (const float*)d_in[6];
    const float* c3w  = (const float*)d_in[8];
    const float* c0b  = (const float*)d_in[3];
    const float* c1b  = (const float*)d_in[5];
    const float* c2b  = (const float*)d_in[7];
    const float* c3b  = (const float*)d_in[9];
    const float* w1   = (const float*)d_in[10];
    const float* b1   = (const float*)d_in[11];
    const float* w2   = (const float*)d_in[12];
    const float* b2   = (const float*)d_in[13];
    float* out = (float*)d_out;

    char* ws = (char*)d_ws;
    _Float16* xh = (_Float16*)ws;                         // 8 MB
    _Float16* fA = (_Float16*)(ws + (8u << 20));          // 8 MB
    _Float16* fB = (_Float16*)(ws + (16u << 20));         // 8 MB
    half8* w2p   = (half8*)(ws + (24u << 20));            // 221184 B
    float* b2p   = (float*)(ws + (24u << 20) + 221184);   // 1728 B
    half8* wpk   = (half8*)(ws + (24u << 20) + 221184 + 1728);  // 20480 B

    xcvt<<<1024, 256, 0, stream>>>(x, xh);
    pack_all<<<59, 256, 0, stream>>>(w2, b2, w2p, b2p, c0w, c1w, c2w, c3w, wpk);

    conv_mfma<<<1024, 256, 0, stream>>>(xh, wpk,         c0b, fA);
    conv_mfma<<<1024, 256, 0, stream>>>(fA, wpk + 320,   c1b, fB);
    conv_mfma<<<1024, 256, 0, stream>>>(fB, wpk + 640,   c2b, fA);
    conv_mfma<<<1024, 256, 0, stream>>>(fA, wpk + 960,   c3b, fB);

    mlp_lc_mfma<<<4096, 512, 0, stream>>>(pos, w1, b1, w2p, b2p, fB, out);
}

// Round 13
// 156.428 us; speedup vs baseline: 1.0160x; 1.0160x over previous
//
#include <hip/hip_runtime.h>
#include <string.h>

typedef _Float16 half2v __attribute__((ext_vector_type(2)));
typedef _Float16 half4  __attribute__((ext_vector_type(4)));
typedef _Float16 half8  __attribute__((ext_vector_type(8)));
typedef float    float4v __attribute__((ext_vector_type(4)));
typedef unsigned int uint4v __attribute__((ext_vector_type(4)));

#define HH 256
#define WW 256
#define HSTR 264   // R5-proven h_lds row stride (268 measured slower — R9)

static __device__ inline half2v pkrtz(float a, float b) {
    return __builtin_bit_cast(half2v, __builtin_amdgcn_cvt_pkrtz(a, b));
}

static __device__ inline half2v h2cast(unsigned u) {
    return __builtin_bit_cast(half2v, u);
}

static __device__ inline float fdot2f(half2v a, half2v b, float c) {
#if __has_builtin(__builtin_amdgcn_fdot2)
    return __builtin_amdgcn_fdot2(__builtin_bit_cast(__fp16 __attribute__((ext_vector_type(2))), a),
                                  __builtin_bit_cast(__fp16 __attribute__((ext_vector_type(2))), b),
                                  c, false);
#else
    return c + (float)a[0] * (float)b[0] + (float)a[1] * (float)b[1];
#endif
}

// ------- fused prep: x->NHWC f16 cvt (blocks 0..1023) + weight packing -----
__global__ __launch_bounds__(256) void prep_all(
    const float* __restrict__ x, _Float16* __restrict__ xh,
    const float* __restrict__ w2, const float* __restrict__ b2,
    half8* __restrict__ w2p, float* __restrict__ b2p,
    const float* __restrict__ w0, const float* __restrict__ w1c,
    const float* __restrict__ w2c, const float* __restrict__ w3c,
    half8* __restrict__ wpk)
{
    const int b = blockIdx.x;
    if (b < 1024) {
        int gid = b * 256 + threadIdx.x;           // n*65536 + y*256 + x
        int px = gid & 65535, n = gid >> 16;
        float r = x[n * 196608 + px];
        float g = x[n * 196608 + 65536 + px];
        float bb = x[n * 196608 + 131072 + px];
        half2v p0 = pkrtz(r, g);
        half2v p1 = pkrtz(bb, 0.f);
        unsigned u0, u1;
        memcpy(&u0, &p0, 4); memcpy(&u1, &p1, 4);
        uint4v v0 = {u0, u1, 0u, 0u};
        uint4v v1 = {0u, 0u, 0u, 0u};
        uint4v* dst = (uint4v*)&xh[(long)gid * 16];
        dst[0] = v0; dst[1] = v1;
        return;
    }
    int tid = (b - 1024) * 256 + threadIdx.x;
    if (tid < 13824) {
        int l  = tid & 63;
        int s  = (tid >> 6) & 7;
        int tt = tid >> 9;                           // tile 0..26
        int kk = tt / 3, c = tt % 3;
        int ci = l & 15;
        int col = (ci * 9 + kk) * 3 + c;
        int kbase = s * 32 + (l >> 4) * 8;
        half8 h;
#pragma unroll
        for (int j = 0; j < 8; ++j)
            h[j] = (_Float16)w2[(kbase + j) * 432 + col];
        w2p[tid] = h;

        if (tid < 432) {
            int tt2 = tid >> 4, ci2 = tid & 15;
            int kk2 = tt2 / 3, c2 = tt2 % 3;
            b2p[tid] = b2[(ci2 * 9 + kk2) * 3 + c2];
        }
    } else if (tid < 15104) {
        int t2 = tid - 13824;                        // < 1280
        int l = t2 & 63, s = (t2 >> 6) % 5, cv = t2 / 320;
        const float* w = (cv == 0) ? w0 : (cv == 1) ? w1c : (cv == 2) ? w2c : w3c;
        int CIN = (cv == 0) ? 3 : 16;
        int o = l & 15, hi = l >> 4;
        half8 h;
#pragma unroll
        for (int j = 0; j < 8; ++j) {
            int k = 32 * s + hi * 8 + j;
            int tap = k >> 4, ci = k & 15;
            float v = 0.f;
            if (tap < 9 && ci < CIN)
                v = w[((o * CIN + ci) * 3 + tap / 3) * 3 + tap % 3];
            h[j] = (_Float16)v;
        }
        wpk[t2] = h;
    }
}

// ---------------- conv 3x3 + ReLU via implicit-GEMM MFMA, NHWC f16 ---------
__global__ __launch_bounds__(256) void conv_mfma(
    const _Float16* __restrict__ in, const half8* __restrict__ wpk,
    const float* __restrict__ bias, _Float16* __restrict__ outp)
{
    __shared__ _Float16 tile[7][66][16];           // 14784 B

    const int t = threadIdx.x;
    const int bid = blockIdx.x;
    const int xt = bid & 3, yt = (bid >> 2) & 63, n = bid >> 8;
    const int x0 = xt * 64, y0 = yt * 4;

    for (int e = t; e < 462; e += 256) {           // 7 rows x 66 x, 32B chunks
        int xx = e % 66, row = e / 66;
        int gy = y0 + row - 1, gx = x0 + xx - 1;
        uint4v v0 = {0u,0u,0u,0u}, v1 = {0u,0u,0u,0u};
        if (gy >= 0 && gy < HH && gx >= 0 && gx < WW) {
            const uint4v* src = (const uint4v*)&in[(((long)(n*HH+gy))*WW + gx) * 16];
            v0 = src[0]; v1 = src[1];
        }
        uint4v* dst = (uint4v*)&tile[row][xx][0];
        dst[0] = v0; dst[1] = v1;
    }
    __syncthreads();

    const int wid = t >> 6, lane = t & 63;
    const int l15 = lane & 15, hi = lane >> 4;

    half8 af[5];
#pragma unroll
    for (int s = 0; s < 5; ++s) af[s] = wpk[s * 64 + lane];
    const float4v bini = *(const float4v*)&bias[hi * 4];

    const int ty = wid;
    const half8* bp = (const half8*)&tile[0][0][0];
#pragma unroll
    for (int tx = 0; tx < 4; ++tx) {
        float4v acc = bini;
#pragma unroll
        for (int s = 0; s < 5; ++s) {
            int tap = 2 * s + (hi >> 1);
            int dyq = (tap * 11) >> 5;             // tap / 3
            int dxr = tap - dyq * 3;
            int cell = (ty + dyq) * 66 + (tx * 16 + l15 + dxr);
            half8 bf = bp[cell * 2 + (hi & 1)];
            acc = __builtin_amdgcn_mfma_f32_16x16x32_f16(af[s], bf, acc, 0, 0, 0);
        }
        int gx = x0 + tx * 16 + l15, gy = y0 + ty;
        half2v p0 = pkrtz(fmaxf(acc[0], 0.f), fmaxf(acc[1], 0.f));
        half2v p1 = pkrtz(fmaxf(acc[2], 0.f), fmaxf(acc[3], 0.f));
        half4 ov = __builtin_shufflevector(p0, p1, 0, 1, 2, 3);
        *(half4*)&outp[(((long)(n*HH+gy))*WW + gx) * 16 + hi * 4] = ov;
    }
}

// ---- fused Pos2Weight MLP (MFMA) + locally-connected contraction ----------
// R12 base (mlp=143us; 64 arch + 64 acc = 128-reg quantum, 16 waves/CU) with
// ONE change: s_setprio(1) around each ks-step's MFMA cluster (T5 — the CU
// runs 2 independent barrier-groups, so priority arbitration has a target).
__global__ __launch_bounds__(512, 4) void mlp_lc_mfma(
    const float* __restrict__ pos, const float* __restrict__ w1,
    const float* __restrict__ b1,  const half8* __restrict__ w2p,
    const float* __restrict__ b2p, const _Float16* __restrict__ f,
    float* __restrict__ out)
{
    __shared__ __attribute__((aligned(16))) char smem[47872];
    _Float16* h_lds    = (_Float16*)smem;                  // [64][264] 33792 B
    unsigned* f_u32    = (unsigned*)(smem + 33792);        // 102 cells x 32 u32, 13056 B
    float*    pos_lds  = (float*)(smem + 33792 + 13056);   // [64][4] 1024 B
    float*    part_lds = (float*)smem;                     // [64][106] alias

    const int t = threadIdx.x;
    // XCD-chunked swizzle: each XCD owns a contiguous slab of logical work
    const int bid = blockIdx.x;
    const int lb  = (bid & 7) * 512 + (bid >> 3);
    const int p0  = lb * 64;
    const int t2  = p0 >> 9;                  // output row oy
    const int hh  = t2 >> 1;
    const int ww0 = (p0 >> 1) & (WW - 1);

    if (t < 192) pos_lds[(t / 3) * 4 + (t % 3)] = pos[p0 * 3 + t];

    // stage f: 408 threads = 102 (dy,x) cells x 4 n; 32B global chunk each,
    // scattered into the cell as 8 swizzled b32 words
    if (t < 408) {
        int n  = t & 3;
        int q  = t >> 2;                      // cell = dy*34 + x
        int x  = q % 34;
        int dy = q / 34;
        int gy = hh + dy - 1, gx = ww0 + x - 1;
        uint4v v0 = {0u,0u,0u,0u}, v1 = {0u,0u,0u,0u};
        if (gy >= 0 && gy < HH && gx >= 0 && gx < WW) {
            const uint4v* src = (const uint4v*)&f[(((long)(n*HH+gy))*WW + gx) * 16];
            v0 = src[0]; v1 = src[1];
        }
        const int base = q * 32;
        const int key  = (q & 7) << 2;
#pragma unroll
        for (int g = 0; g < 4; ++g)
            f_u32[base + ((g * 4 + n) ^ key)] = v0[g];
#pragma unroll
        for (int g = 4; g < 8; ++g)
            f_u32[base + ((g * 4 + n) ^ key)] = v1[g - 4];
    }
    __syncthreads();                          // pos + f ready

    // ---- h = relu(pos @ w1 + b1): 4 k x 8 pos per thread, b64 writes ----
    {
        const int k4 = (t & 63) * 4;          // lane-contiguous k block
        const int i0 = (t >> 6) * 8;          // 8 positions per thread
        const float4v w1r0 = *(const float4v*)&w1[k4];
        const float4v w1r1 = *(const float4v*)&w1[256 + k4];
        const float4v w1r2 = *(const float4v*)&w1[512 + k4];
        const float4v b1v  = *(const float4v*)&b1[k4];
#pragma unroll
        for (int i = i0; i < i0 + 8; ++i) {
            float4v pv = *(const float4v*)&pos_lds[i * 4];
            float a0 = fmaf(pv[0], w1r0[0], fmaf(pv[1], w1r1[0], fmaf(pv[2], w1r2[0], b1v[0])));
            float a1 = fmaf(pv[0], w1r0[1], fmaf(pv[1], w1r1[1], fmaf(pv[2], w1r2[1], b1v[1])));
            float a2 = fmaf(pv[0], w1r0[2], fmaf(pv[1], w1r1[2], fmaf(pv[2], w1r2[2], b1v[2])));
            float a3 = fmaf(pv[0], w1r0[3], fmaf(pv[1], w1r1[3], fmaf(pv[2], w1r2[3], b1v[3])));
            half2v q0 = pkrtz(fmaxf(a0, 0.f), fmaxf(a1, 0.f));
            half2v q1 = pkrtz(fmaxf(a2, 0.f), fmaxf(a3, 0.f));
            *(half4*)&h_lds[i * HSTR + k4] = __builtin_shufflevector(q0, q1, 0, 1, 2, 3);
        }
    }
    __syncthreads();                          // h ready

    // ---- GEMM: acc[tt][pg] = w2tile(tb+tt)^T @ h(pg) ----
    const int wid  = t >> 6;
    const int lane = t & 63;
    const int l15  = lane & 15, hi = lane >> 4;
    const int tb   = (wid <= 3) ? wid * 4 : 12 + (wid - 3) * 3;
    const int cnt  = (wid < 3) ? 4 : 3;

    float4v acc[4][4];
#pragma unroll
    for (int tt = 0; tt < 4; ++tt)
        if (tt < cnt) {
            float4v binit = *(const float4v*)&b2p[(tb + tt) * 16 + hi * 4];
#pragma unroll
            for (int pg = 0; pg < 4; ++pg) acc[tt][pg] = binit;
        }

    for (int ks = 0; ks < 8; ++ks) {
        half8 bfrag[4];
#pragma unroll
        for (int pg = 0; pg < 4; ++pg)
            bfrag[pg] = *(const half8*)&h_lds[(pg * 16 + l15) * HSTR + ks * 32 + hi * 8];
        __builtin_amdgcn_s_setprio(1);
#pragma unroll
        for (int tt = 0; tt < 4; ++tt)
            if (tt < cnt) {
                half8 afrag = w2p[((tb + tt) * 8 + ks) * 64 + lane];
#pragma unroll
                for (int pg = 0; pg < 4; ++pg)
                    acc[tt][pg] = __builtin_amdgcn_mfma_f32_16x16x32_f16(
                        afrag, bfrag[pg], acc[tt][pg], 0, 0, 0);
            }
        __builtin_amdgcn_s_setprio(0);
    }
    __syncthreads();   // all h reads done; part_lds (alias) may be written

    // ---- epilogue: b128 f reads, fdot2 contraction, reduce ------
    const int r3 = tb % 3;            // wave-uniform rgb rotation
    int dy_t[4], dx_t[4];
#pragma unroll
    for (int tt = 0; tt < 4; ++tt) {
        int kk = (tb + tt) / 3;
        dy_t[tt] = kk / 3;
        dx_t[tt] = kk % 3;
    }

#pragma unroll
    for (int pg = 0; pg < 4; ++pg) {
        const int posl = pg * 16 + l15;
        const int xloc = posl >> 1;

        float part[4][3];
#pragma unroll
        for (int n = 0; n < 4; ++n)
#pragma unroll
            for (int c = 0; c < 3; ++c) part[n][c] = 0.f;

#pragma unroll
        for (int tt = 0; tt < 4; ++tt)
            if (tt < cnt) {
                int x    = xloc + dx_t[tt];
                int cell = dy_t[tt] * 34 + x;
                int key  = cell & 7;
                const uint4v* fcell = (const uint4v*)(f_u32 + cell * 32);
                uint4v fv0 = fcell[(2 * hi) ^ key];       // ci 4hi,4hi+1, n lanes
                uint4v fv1 = fcell[(2 * hi + 1) ^ key];   // ci 4hi+2,4hi+3
                half2v ap = pkrtz(acc[tt][pg][0], acc[tt][pg][1]);
                half2v bq = pkrtz(acc[tt][pg][2], acc[tt][pg][3]);
                const int u = tt % 3;
#pragma unroll
                for (int n = 0; n < 4; ++n)
                    part[n][u] = fdot2f(h2cast(fv0[n]), ap,
                                 fdot2f(h2cast(fv1[n]), bq, part[n][u]));
            }

        float real[4][3];
        if (r3 == 0) {
#pragma unroll
            for (int n = 0; n < 4; ++n) {
                real[n][0] = part[n][0]; real[n][1] = part[n][1]; real[n][2] = part[n][2];
            }
        } else if (r3 == 1) {
#pragma unroll
            for (int n = 0; n < 4; ++n) {
                real[n][1] = part[n][0]; real[n][2] = part[n][1]; real[n][0] = part[n][2];
            }
        } else {
#pragma unroll
            for (int n = 0; n < 4; ++n) {
                real[n][2] = part[n][0]; real[n][0] = part[n][1]; real[n][1] = part[n][2];
            }
        }

#pragma unroll
        for (int n = 0; n < 4; ++n)
#pragma unroll
            for (int c = 0; c < 3; ++c) {
                float v = real[n][c];
                v += __shfl_xor(v, 16);
                v += __shfl_xor(v, 32);
                if (hi == 0)
                    part_lds[posl * 106 + (n * 3 + c) * 8 + wid] = v;
            }
    }
    __syncthreads();

    // ---- combine 8 waves' partials, add mean, store ----
    for (int e = t; e < 768; e += 512) {
        int posl = e & 63;
        int j = e >> 6;                       // n*3+c
        const float* pr = &part_lds[posl * 106 + j * 8];
        float4v v0 = *(const float4v*)pr;
        float4v v1 = *(const float4v*)(pr + 4);
        float v = v0[0] + v0[1] + v0[2] + v0[3] + v1[0] + v1[1] + v1[2] + v1[3];
        int n = j / 3, c = j - 3 * n;
        float mean = (c == 0) ? 114.4440f : (c == 1) ? 111.4605f : 103.0200f;
        out[((n * 3 + c) * 512 + t2) * 512 + (ww0 * 2 + posl)] = v + mean;
    }
}

extern "C" void kernel_launch(void* const* d_in, const int* in_sizes, int n_in,
                              void* d_out, int out_size, void* d_ws, size_t ws_size,
                              hipStream_t stream) {
    const float* x    = (const float*)d_in[0];
    const float* pos  = (const float*)d_in[1];
    const float* c0w  = (const float*)d_in[2];
    const float* c1w  = (const float*)d_in[4];
    const float* c2w  = (const float*)d_in[6];
    const float* c3w  = (const float*)d_in[8];
    const float* c0b  = (const float*)d_in[3];
    const float* c1b  = (const float*)d_in[5];
    const float* c2b  = (const float*)d_in[7];
    const float* c3b  = (const float*)d_in[9];
    const float* w1   = (const float*)d_in[10];
    const float* b1   = (const float*)d_in[11];
    const float* w2   = (const float*)d_in[12];
    const float* b2   = (const float*)d_in[13];
    float* out = (float*)d_out;

    char* ws = (char*)d_ws;
    _Float16* xh = (_Float16*)ws;                         // 8 MB
    _Float16* fA = (_Float16*)(ws + (8u << 20));          // 8 MB
    _Float16* fB = (_Float16*)(ws + (16u << 20));         // 8 MB
    half8* w2p   = (half8*)(ws + (24u << 20));            // 221184 B
    float* b2p   = (float*)(ws + (24u << 20) + 221184);   // 1728 B
    half8* wpk   = (half8*)(ws + (24u << 20) + 221184 + 1728);  // 20480 B

    prep_all<<<1024 + 59, 256, 0, stream>>>(x, xh, w2, b2, w2p, b2p,
                                            c0w, c1w, c2w, c3w, wpk);

    conv_mfma<<<1024, 256, 0, stream>>>(xh, wpk,         c0b, fA);
    conv_mfma<<<1024, 256, 0, stream>>>(fA, wpk + 320,   c1b, fB);
    conv_mfma<<<1024, 256, 0, stream>>>(fB, wpk + 640,   c2b, fA);
    conv_mfma<<<1024, 256, 0, stream>>>(fA, wpk + 960,   c3b, fB);

    mlp_lc_mfma<<<4096, 512, 0, stream>>>(pos, w1, b1, w2p, b2p, fB, out);
}

// Round 14
// 150.217 us; speedup vs baseline: 1.0580x; 1.0413x over previous
//
#include <hip/hip_runtime.h>
#include <string.h>

typedef _Float16 half2v __attribute__((ext_vector_type(2)));
typedef _Float16 half4  __attribute__((ext_vector_type(4)));
typedef _Float16 half8  __attribute__((ext_vector_type(8)));
typedef float    float4v __attribute__((ext_vector_type(4)));
typedef unsigned int uint4v __attribute__((ext_vector_type(4)));

#define HH 256
#define WW 256
#define HSTR 264

static __device__ inline half2v pkrtz(float a, float b) {
    return __builtin_bit_cast(half2v, __builtin_amdgcn_cvt_pkrtz(a, b));
}

static __device__ inline half2v h2cast(unsigned u) {
    return __builtin_bit_cast(half2v, u);
}

static __device__ inline float fdot2f(half2v a, half2v b, float c) {
#if __has_builtin(__builtin_amdgcn_fdot2)
    return __builtin_amdgcn_fdot2(__builtin_bit_cast(__fp16 __attribute__((ext_vector_type(2))), a),
                                  __builtin_bit_cast(__fp16 __attribute__((ext_vector_type(2))), b),
                                  c, false);
#else
    return c + (float)a[0] * (float)b[0] + (float)a[1] * (float)b[1];
#endif
}

// ------- fused prep: x->NHWC f16 cvt (blocks 0..1023) + weight packing -----
__global__ __launch_bounds__(256) void prep_all(
    const float* __restrict__ x, _Float16* __restrict__ xh,
    const float* __restrict__ w2, const float* __restrict__ b2,
    half8* __restrict__ w2p, float* __restrict__ b2p,
    const float* __restrict__ w0, const float* __restrict__ w1c,
    const float* __restrict__ w2c, const float* __restrict__ w3c,
    half8* __restrict__ wpk)
{
    const int b = blockIdx.x;
    if (b < 1024) {
        int gid = b * 256 + threadIdx.x;           // n*65536 + y*256 + x
        int px = gid & 65535, n = gid >> 16;
        float r = x[n * 196608 + px];
        float g = x[n * 196608 + 65536 + px];
        float bb = x[n * 196608 + 131072 + px];
        half2v p0 = pkrtz(r, g);
        half2v p1 = pkrtz(bb, 0.f);
        unsigned u0, u1;
        memcpy(&u0, &p0, 4); memcpy(&u1, &p1, 4);
        uint4v v0 = {u0, u1, 0u, 0u};
        uint4v v1 = {0u, 0u, 0u, 0u};
        uint4v* dst = (uint4v*)&xh[(long)gid * 16];
        dst[0] = v0; dst[1] = v1;
        return;
    }
    int tid = (b - 1024) * 256 + threadIdx.x;
    if (tid < 13824) {
        int l  = tid & 63;
        int s  = (tid >> 6) & 7;
        int tt = tid >> 9;                           // tile 0..26
        int kk = tt / 3, c = tt % 3;
        int ci = l & 15;
        int col = (ci * 9 + kk) * 3 + c;
        int kbase = s * 32 + (l >> 4) * 8;
        half8 h;
#pragma unroll
        for (int j = 0; j < 8; ++j)
            h[j] = (_Float16)w2[(kbase + j) * 432 + col];
        w2p[tid] = h;

        if (tid < 432) {
            int tt2 = tid >> 4, ci2 = tid & 15;
            int kk2 = tt2 / 3, c2 = tt2 % 3;
            b2p[tid] = b2[(ci2 * 9 + kk2) * 3 + c2];
        }
    } else if (tid < 15104) {
        int t2 = tid - 13824;                        // < 1280
        int l = t2 & 63, s = (t2 >> 6) % 5, cv = t2 / 320;
        const float* w = (cv == 0) ? w0 : (cv == 1) ? w1c : (cv == 2) ? w2c : w3c;
        int CIN = (cv == 0) ? 3 : 16;
        int o = l & 15, hi = l >> 4;
        half8 h;
#pragma unroll
        for (int j = 0; j < 8; ++j) {
            int k = 32 * s + hi * 8 + j;
            int tap = k >> 4, ci = k & 15;
            float v = 0.f;
            if (tap < 9 && ci < CIN)
                v = w[((o * CIN + ci) * 3 + tap / 3) * 3 + tap % 3];
            h[j] = (_Float16)v;
        }
        wpk[t2] = h;
    }
}

// ---------------- conv 3x3 + ReLU via implicit-GEMM MFMA, NHWC f16 ---------
__global__ __launch_bounds__(256) void conv_mfma(
    const _Float16* __restrict__ in, const half8* __restrict__ wpk,
    const float* __restrict__ bias, _Float16* __restrict__ outp)
{
    __shared__ _Float16 tile[7][66][16];           // 14784 B

    const int t = threadIdx.x;
    const int bid = blockIdx.x;
    const int xt = bid & 3, yt = (bid >> 2) & 63, n = bid >> 8;
    const int x0 = xt * 64, y0 = yt * 4;

    for (int e = t; e < 462; e += 256) {           // 7 rows x 66 x, 32B chunks
        int xx = e % 66, row = e / 66;
        int gy = y0 + row - 1, gx = x0 + xx - 1;
        uint4v v0 = {0u,0u,0u,0u}, v1 = {0u,0u,0u,0u};
        if (gy >= 0 && gy < HH && gx >= 0 && gx < WW) {
            const uint4v* src = (const uint4v*)&in[(((long)(n*HH+gy))*WW + gx) * 16];
            v0 = src[0]; v1 = src[1];
        }
        uint4v* dst = (uint4v*)&tile[row][xx][0];
        dst[0] = v0; dst[1] = v1;
    }
    __syncthreads();

    const int wid = t >> 6, lane = t & 63;
    const int l15 = lane & 15, hi = lane >> 4;

    half8 af[5];
#pragma unroll
    for (int s = 0; s < 5; ++s) af[s] = wpk[s * 64 + lane];
    const float4v bini = *(const float4v*)&bias[hi * 4];

    const int ty = wid;
    const half8* bp = (const half8*)&tile[0][0][0];
#pragma unroll
    for (int tx = 0; tx < 4; ++tx) {
        float4v acc = bini;
#pragma unroll
        for (int s = 0; s < 5; ++s) {
            int tap = 2 * s + (hi >> 1);
            int dyq = (tap * 11) >> 5;             // tap / 3
            int dxr = tap - dyq * 3;
            int cell = (ty + dyq) * 66 + (tx * 16 + l15 + dxr);
            half8 bf = bp[cell * 2 + (hi & 1)];
            acc = __builtin_amdgcn_mfma_f32_16x16x32_f16(af[s], bf, acc, 0, 0, 0);
        }
        int gx = x0 + tx * 16 + l15, gy = y0 + ty;
        half2v p0 = pkrtz(fmaxf(acc[0], 0.f), fmaxf(acc[1], 0.f));
        half2v p1 = pkrtz(fmaxf(acc[2], 0.f), fmaxf(acc[3], 0.f));
        half4 ov = __builtin_shufflevector(p0, p1, 0, 1, 2, 3);
        *(half4*)&outp[(((long)(n*HH+gy))*WW + gx) * 16 + hi * 4] = ov;
    }
}

// ---- fused Pos2Weight MLP (MFMA) + locally-connected contraction ----------
// 256 thr / 4 waves, 32 positions, 8192 blocks -> 4 independent barrier
// groups per CU (was 2). Waves 0-2: 7 col-tiles, wave 3: 6. acc[7][2] = 56
// f32; afrag loaded one-at-a-time -> total regs <= 128 quantum.
__global__ __launch_bounds__(256, 4) void mlp_lc_mfma(
    const float* __restrict__ pos, const float* __restrict__ w1,
    const float* __restrict__ b1,  const half8* __restrict__ w2p,
    const float* __restrict__ b2p, const _Float16* __restrict__ f,
    float* __restrict__ out)
{
    __shared__ __attribute__((aligned(16))) char smem[24320];
    _Float16* h_lds    = (_Float16*)smem;                  // [32][264] 16896 B
    unsigned* f_u32    = (unsigned*)(smem + 16896);        // 54 cells x 32 u32, 6912 B
    float*    pos_lds  = (float*)(smem + 16896 + 6912);    // [32][4] 512 B
    float*    part_lds = (float*)smem;                     // [32][49] alias (6272 B)

    const int t = threadIdx.x;
    const int bid = blockIdx.x;
    const int lb  = (bid & 7) * 1024 + (bid >> 3);         // XCD-chunked swizzle
    const int p0  = lb * 32;
    const int t2  = p0 >> 9;                  // output row oy
    const int hh  = t2 >> 1;
    const int ww0 = (p0 >> 1) & (WW - 1);     // 16-px x-tile base

    if (t < 96) pos_lds[(t / 3) * 4 + (t % 3)] = pos[p0 * 3 + t];

    // stage f: 216 threads = 54 (dy,x) cells x 4 n; 32B global chunk each
    if (t < 216) {
        int n  = t & 3;
        int q  = t >> 2;                      // cell = dy*18 + x
        int x  = q % 18;
        int dy = q / 18;
        int gy = hh + dy - 1, gx = ww0 + x - 1;
        uint4v v0 = {0u,0u,0u,0u}, v1 = {0u,0u,0u,0u};
        if (gy >= 0 && gy < HH && gx >= 0 && gx < WW) {
            const uint4v* src = (const uint4v*)&f[(((long)(n*HH+gy))*WW + gx) * 16];
            v0 = src[0]; v1 = src[1];
        }
        const int base = q * 32;
        const int key  = (q & 7) << 2;
#pragma unroll
        for (int g = 0; g < 4; ++g)
            f_u32[base + ((g * 4 + n) ^ key)] = v0[g];
#pragma unroll
        for (int g = 4; g < 8; ++g)
            f_u32[base + ((g * 4 + n) ^ key)] = v1[g - 4];
    }
    __syncthreads();                          // pos + f ready

    // ---- h = relu(pos @ w1 + b1): 4 k x 8 pos per thread, b64 writes ----
    {
        const int k4 = (t & 63) * 4;
        const int i0 = (t >> 6) * 8;          // 4 groups x 8 positions = 32
        const float4v w1r0 = *(const float4v*)&w1[k4];
        const float4v w1r1 = *(const float4v*)&w1[256 + k4];
        const float4v w1r2 = *(const float4v*)&w1[512 + k4];
        const float4v b1v  = *(const float4v*)&b1[k4];
#pragma unroll
        for (int i = i0; i < i0 + 8; ++i) {
            float4v pv = *(const float4v*)&pos_lds[i * 4];
            float a0 = fmaf(pv[0], w1r0[0], fmaf(pv[1], w1r1[0], fmaf(pv[2], w1r2[0], b1v[0])));
            float a1 = fmaf(pv[0], w1r0[1], fmaf(pv[1], w1r1[1], fmaf(pv[2], w1r2[1], b1v[1])));
            float a2 = fmaf(pv[0], w1r0[2], fmaf(pv[1], w1r1[2], fmaf(pv[2], w1r2[2], b1v[2])));
            float a3 = fmaf(pv[0], w1r0[3], fmaf(pv[1], w1r1[3], fmaf(pv[2], w1r2[3], b1v[3])));
            half2v q0 = pkrtz(fmaxf(a0, 0.f), fmaxf(a1, 0.f));
            half2v q1 = pkrtz(fmaxf(a2, 0.f), fmaxf(a3, 0.f));
            *(half4*)&h_lds[i * HSTR + k4] = __builtin_shufflevector(q0, q1, 0, 1, 2, 3);
        }
    }
    __syncthreads();                          // h ready

    // ---- GEMM: acc[tt][pg] = w2tile(tb+tt)^T @ h(pg) ----
    const int wid  = t >> 6;
    const int lane = t & 63;
    const int l15  = lane & 15, hi = lane >> 4;
    const int tb   = wid * 7;                 // 0,7,14,21 (wave 3: 6 tiles)
    const int cnt  = (wid < 3) ? 7 : 6;

    float4v acc[7][2];
#pragma unroll
    for (int tt = 0; tt < 7; ++tt)
        if (tt < cnt) {
            float4v binit = *(const float4v*)&b2p[(tb + tt) * 16 + hi * 4];
            acc[tt][0] = binit;
            acc[tt][1] = binit;
        }

    for (int ks = 0; ks < 8; ++ks) {
        half8 bfrag[2];
#pragma unroll
        for (int pg = 0; pg < 2; ++pg)
            bfrag[pg] = *(const half8*)&h_lds[(pg * 16 + l15) * HSTR + ks * 32 + hi * 8];
#pragma unroll
        for (int tt = 0; tt < 7; ++tt)
            if (tt < cnt) {
                half8 afrag = w2p[((tb + tt) * 8 + ks) * 64 + lane];
                acc[tt][0] = __builtin_amdgcn_mfma_f32_16x16x32_f16(
                    afrag, bfrag[0], acc[tt][0], 0, 0, 0);
                acc[tt][1] = __builtin_amdgcn_mfma_f32_16x16x32_f16(
                    afrag, bfrag[1], acc[tt][1], 0, 0, 0);
            }
    }
    __syncthreads();   // all h reads done; part_lds (alias) may be written

    // ---- epilogue: b128 f reads, fdot2 contraction, reduce ------
    const int r3 = tb % 3;            // wave-uniform rgb rotation
    int dy_t[7], dx_t[7];
#pragma unroll
    for (int tt = 0; tt < 7; ++tt) {
        int kk = (tb + tt) / 3;
        dy_t[tt] = kk / 3;
        dx_t[tt] = kk % 3;
    }

#pragma unroll
    for (int pg = 0; pg < 2; ++pg) {
        const int posl = pg * 16 + l15;
        const int xloc = posl >> 1;

        float part[4][3];
#pragma unroll
        for (int n = 0; n < 4; ++n)
#pragma unroll
            for (int c = 0; c < 3; ++c) part[n][c] = 0.f;

#pragma unroll
        for (int tt = 0; tt < 7; ++tt)
            if (tt < cnt) {
                int x    = xloc + dx_t[tt];
                int cell = dy_t[tt] * 18 + x;
                int key  = cell & 7;
                const uint4v* fcell = (const uint4v*)(f_u32 + cell * 32);
                uint4v fv0 = fcell[(2 * hi) ^ key];       // ci 4hi,4hi+1, n lanes
                uint4v fv1 = fcell[(2 * hi + 1) ^ key];   // ci 4hi+2,4hi+3
                half2v ap = pkrtz(acc[tt][pg][0], acc[tt][pg][1]);
                half2v bq = pkrtz(acc[tt][pg][2], acc[tt][pg][3]);
                const int u = tt % 3;
#pragma unroll
                for (int n = 0; n < 4; ++n)
                    part[n][u] = fdot2f(h2cast(fv0[n]), ap,
                                 fdot2f(h2cast(fv1[n]), bq, part[n][u]));
            }

        float real[4][3];
        if (r3 == 0) {
#pragma unroll
            for (int n = 0; n < 4; ++n) {
                real[n][0] = part[n][0]; real[n][1] = part[n][1]; real[n][2] = part[n][2];
            }
        } else if (r3 == 1) {
#pragma unroll
            for (int n = 0; n < 4; ++n) {
                real[n][1] = part[n][0]; real[n][2] = part[n][1]; real[n][0] = part[n][2];
            }
        } else {
#pragma unroll
            for (int n = 0; n < 4; ++n) {
                real[n][2] = part[n][0]; real[n][0] = part[n][1]; real[n][1] = part[n][2];
            }
        }

#pragma unroll
        for (int n = 0; n < 4; ++n)
#pragma unroll
            for (int c = 0; c < 3; ++c) {
                float v = real[n][c];
                v += __shfl_xor(v, 16);
                v += __shfl_xor(v, 32);
                if (hi == 0)
                    part_lds[posl * 49 + (n * 3 + c) * 4 + wid] = v;
            }
    }
    __syncthreads();

    // ---- combine 4 waves' partials, add mean, store ----
    for (int e = t; e < 384; e += 256) {
        int posl = e & 31;
        int j = e >> 5;                       // n*3+c, 0..11
        const float* pr = &part_lds[posl * 49 + j * 4];
        float4v v0 = *(const float4v*)pr;
        float v = v0[0] + v0[1] + v0[2] + v0[3];
        int n = j / 3, c = j - 3 * n;
        float mean = (c == 0) ? 114.4440f : (c == 1) ? 111.4605f : 103.0200f;
        out[((n * 3 + c) * 512 + t2) * 512 + (ww0 * 2 + posl)] = v + mean;
    }
}

extern "C" void kernel_launch(void* const* d_in, const int* in_sizes, int n_in,
                              void* d_out, int out_size, void* d_ws, size_t ws_size,
                              hipStream_t stream) {
    const float* x    = (const float*)d_in[0];
    const float* pos  = (const float*)d_in[1];
    const float* c0w  = (const float*)d_in[2];
    const float* c1w  = (const float*)d_in[4];
    const float* c2w  = (const float*)d_in[6];
    const float* c3w  = (const float*)d_in[8];
    const float* c0b  = (const float*)d_in[3];
    const float* c1b  = (const float*)d_in[5];
    const float* c2b  = (const float*)d_in[7];
    const float* c3b  = (const float*)d_in[9];
    const float* w1   = (const float*)d_in[10];
    const float* b1   = (const float*)d_in[11];
    const float* w2   = (const float*)d_in[12];
    const float* b2   = (const float*)d_in[13];
    float* out = (float*)d_out;

    char* ws = (char*)d_ws;
    _Float16* xh = (_Float16*)ws;                         // 8 MB
    _Float16* fA = (_Float16*)(ws + (8u << 20));          // 8 MB
    _Float16* fB = (_Float16*)(ws + (16u << 20));         // 8 MB
    half8* w2p   = (half8*)(ws + (24u << 20));            // 221184 B
    float* b2p   = (float*)(ws + (24u << 20) + 221184);   // 1728 B
    half8* wpk   = (half8*)(ws + (24u << 20) + 221184 + 1728);  // 20480 B

    prep_all<<<1024 + 59, 256, 0, stream>>>(x, xh, w2, b2, w2p, b2p,
                                            c0w, c1w, c2w, c3w, wpk);

    conv_mfma<<<1024, 256, 0, stream>>>(xh, wpk,         c0b, fA);
    conv_mfma<<<1024, 256, 0, stream>>>(fA, wpk + 320,   c1b, fB);
    conv_mfma<<<1024, 256, 0, stream>>>(fB, wpk + 640,   c2b, fA);
    conv_mfma<<<1024, 256, 0, stream>>>(fA, wpk + 960,   c3b, fB);

    mlp_lc_mfma<<<8192, 256, 0, stream>>>(pos, w1, b1, w2p, b2p, fB, out);
}